// Round 18
// baseline (74.561 us; speedup 1.0000x reference)
//
#include <hip/hip_runtime.h>
#include <math.h>

#define PR 30            // padded rows of h2p
#define PC 32            // padded col stride of h2p

// 4px x 3kw taps for one co: window = {a.x,a.y,a.z,a.w,b.x,b.y}
__device__ __forceinline__ void tap3(const float4 a, const float2 b,
                                     const float w0, const float w1, const float w2,
                                     float4& acc) {
    acc.x += fabsf(a.x - w0) + fabsf(a.y - w1) + fabsf(a.z - w2);
    acc.y += fabsf(a.y - w0) + fabsf(a.z - w1) + fabsf(a.w - w2);
    acc.z += fabsf(a.z - w0) + fabsf(a.w - w1) + fabsf(b.x - w2);
    acc.w += fabsf(a.w - w0) + fabsf(b.x - w1) + fabsf(b.y - w2);
}

// =========== KA: 1x1 adder(256->64) + PEG depthwise 3x3 + BN1 + ReLU -> h2p ===========
// grid (16 cog, 2 yh, 8 n) = 256 blocks, block 448. Also emits w2t/w3t transposes.
__global__ __launch_bounds__(448) void ka_fused(const float* __restrict__ x,
                                                const float* __restrict__ w1,
                                                const float* __restrict__ wpeg,
                                                const float* __restrict__ w2,
                                                const float* __restrict__ w3,
                                                const float* __restrict__ g1,
                                                const float* __restrict__ b1,
                                                const float* __restrict__ m1,
                                                const float* __restrict__ v1,
                                                float* __restrict__ h2p,
                                                float* __restrict__ w2t,
                                                float* __restrict__ w3t) {
    __shared__ __align__(16) float smem[3072];   // wsA 1024 + h1t 2048 = 12 KB
    float* wsA = smem;            // [256 ci][4 co]
    float* h1t = smem + 1024;     // [4 co][16 rows][32]
    const int tid    = threadIdx.x;
    const int cobase = blockIdx.x * 4;
    const int yh     = blockIdx.y;
    const int n      = blockIdx.z;
    const int co     = tid / 112;
    const int rem    = tid % 112;
    const int row    = rem / 7;
    const int q      = rem % 7;

    // weight transposes for KB (consumed next launch; stream-ordered)
    {
        const int bid3 = blockIdx.x + 16 * (blockIdx.y + 2 * blockIdx.z);
        const int tg = bid3 * 448 + tid;
        if (tg < 36864) {
            int r = tg >> 6, c2 = tg & 63;
            w2t[tg] = w2[(size_t)c2 * 576 + r];             // w2t[r*64+co]
        } else if (tg < 53248) {
            int i = tg - 36864;
            int ci = i >> 8, c2 = i & 255;
            w3t[i] = w3[(size_t)c2 * 64 + ci];              // w3t[ci*256+co]
        }
    }

    for (int idx = tid; idx < 1024; idx += 448) {
        int c2 = idx >> 8, ci = idx & 255;
        wsA[ci * 4 + c2] = w1[(size_t)(cobase + c2) * 256 + ci];
    }
    for (int idx = tid; idx < 512; idx += 448)
        ((float4*)h1t)[idx] = make_float4(0.f, 0.f, 0.f, 0.f);
    __syncthreads();

    const int gy = yh * 14 - 1 + row;
    if (gy >= 0 && gy < 28) {
        float4 acc = {0.f, 0.f, 0.f, 0.f};
        const float* xp = x + (size_t)n * 256 * 784 + gy * 28 + q * 4;
        #pragma unroll 8
        for (int ci = 0; ci < 256; ++ci) {
            float4 u = *(const float4*)(xp + (size_t)ci * 784);
            float w  = wsA[ci * 4 + co];
            acc.x += fabsf(u.x - w); acc.y += fabsf(u.y - w);
            acc.z += fabsf(u.z - w); acc.w += fabsf(u.w - w);
        }
        float* hd = h1t + co * 512 + row * 32 + 1 + q * 4;
        hd[0] = -acc.x; hd[1] = -acc.y; hd[2] = -acc.z; hd[3] = -acc.w;
    }
    __syncthreads();

    if (row < 14) {
        const int c  = cobase + co;
        const int oy = yh * 14 + row;
        const float* wc = wpeg + c * 9;
        const float* hb = h1t + co * 512 + row * 32 + q * 4;
        float4 acc = {0.f, 0.f, 0.f, 0.f};
        #pragma unroll
        for (int kh = 0; kh < 3; ++kh) {
            float4 a  = *(const float4*)(hb + kh * 32);
            float2 bv = *(const float2*)(hb + kh * 32 + 4);
            tap3(a, bv, wc[kh * 3 + 0], wc[kh * 3 + 1], wc[kh * 3 + 2], acc);
        }
        float inv = g1[c] * rsqrtf(v1[c] + 1e-5f);
        float bb  = b1[c] - m1[c] * inv;
        float* op = h2p + ((size_t)(n * 64 + c) * PR + oy + 1) * PC + 1 + q * 4;
        op[0] = fmaxf(-acc.x * inv + bb, 0.f);
        op[1] = fmaxf(-acc.y * inv + bb, 0.f);
        op[2] = fmaxf(-acc.z * inv + bb, 0.f);
        op[3] = fmaxf(-acc.w * inv + bb, 0.f);
    }
    for (int idx = tid; idx < 352; idx += 448) {
        if (idx < 224) {
            int rr = idx >> 4, k = idx & 15;
            int cc = k >> 2, kk = k & 3;
            int col = kk ? 28 + kk : 0;
            h2p[((size_t)(n * 64 + cobase + cc) * PR + yh * 14 + 1 + rr) * PC + col] = 0.f;
        } else {
            int j = idx - 224;
            int cc = j >> 5, col = j & 31;
            int prow = yh ? 29 : 0;
            h2p[((size_t)(n * 64 + cobase + cc) * PR + prow) * PC + col] = 0.f;
        }
    }
}

// =========== KB: 3x3 adder(64->64)+BN2+ReLU + 1x1 adder(64->256)+BN3+res+ReLU ===========
// grid (28 Y, 8 n) = 224 blocks, block 512 (8 waves).
// Phase A: wave = co-oct (weights WAVE-UNIFORM -> scalar s_load path, no LDS/VALU cost);
//          lane = (ci-half, col). Window = stride-1 scalar LDS (conflict-free).
// Phase B: wave = px-quad-group; h3t broadcast + w3s f4 reads. 2 barriers total.
__global__ __launch_bounds__(512) void kb_fused(const float* __restrict__ h2p,
                                                const float* __restrict__ w2t,
                                                const float* __restrict__ w3t,
                                                const float* __restrict__ x,
                                                const float* __restrict__ g2,
                                                const float* __restrict__ b2,
                                                const float* __restrict__ m2,
                                                const float* __restrict__ v2,
                                                const float* __restrict__ g3,
                                                const float* __restrict__ b3,
                                                const float* __restrict__ m3,
                                                const float* __restrict__ v3,
                                                float* __restrict__ out) {
    __shared__ __align__(16) float h2t[6160];    // [64 ci][96] (3 rows x 32) + pad
    __shared__ __align__(16) float w3s[16896];   // [64 ci][264] (256 co + 8 pad)
    __shared__ __align__(16) float h3t[2048];    // [64 ch][32]
    const int tid = threadIdx.x;
    const int Y   = blockIdx.x;           // output row 0..27
    const int n   = blockIdx.y;

    // stage h2t: padded rows Y..Y+2, 64 ci (f4, coalesced, conflict-free)
    for (int iq = tid; iq < 1536; iq += 512) {
        int ci = iq / 24, r2 = iq % 24;
        int r = r2 >> 3, c4 = r2 & 7;
        *(float4*)(h2t + ci * 96 + r * 32 + c4 * 4) =
            *(const float4*)(h2p + ((size_t)(n * 64 + ci) * PR + Y + r) * PC + c4 * 4);
    }
    // stage w3s from pre-transposed w3t (f4, coalesced)
    for (int iq = tid; iq < 4096; iq += 512) {
        int ci = iq >> 6, cq = iq & 63;
        *(float4*)(w3s + ci * 264 + cq * 4) =
            *(const float4*)(w3t + (size_t)ci * 256 + cq * 4);
    }
    __syncthreads();

    // ---- phase A: 3x3 adder 64->64 ----
    {
        const int lane = tid & 63;
        const int oct  = __builtin_amdgcn_readfirstlane(tid >> 6);  // 0..7, SGPR
        const int col  = lane & 31;       // px (cols 28..31 discarded)
        const int cih  = lane >> 5;       // ci-half
        float a0 = 0.f, a1 = 0.f, a2 = 0.f, a3 = 0.f;
        float a4 = 0.f, a5 = 0.f, a6 = 0.f, a7 = 0.f;
        #pragma unroll 4
        for (int i = 0; i < 32; ++i) {
            const int ci = cih * 32 + i;
            const float* hr = h2t + ci * 96 + col;
            const float* wr = w2t + (size_t)ci * 576 + oct * 8;   // uniform addr
            #pragma unroll
            for (int kh = 0; kh < 3; ++kh) {
                float xw[3];
                xw[0] = hr[kh * 32 + 0];
                xw[1] = hr[kh * 32 + 1];
                xw[2] = hr[kh * 32 + 2];
                #pragma unroll
                for (int kw = 0; kw < 3; ++kw) {
                    const float xv = xw[kw];
                    const float* wt = wr + (kh * 3 + kw) * 64;
                    float4 wa = *(const float4*)(wt);
                    float4 wb = *(const float4*)(wt + 4);
                    a0 += fabsf(xv - wa.x); a1 += fabsf(xv - wa.y);
                    a2 += fabsf(xv - wa.z); a3 += fabsf(xv - wa.w);
                    a4 += fabsf(xv - wb.x); a5 += fabsf(xv - wb.y);
                    a6 += fabsf(xv - wb.z); a7 += fabsf(xv - wb.w);
                }
            }
        }
        // 2-way ci reduce across lane bit 5
        a0 += __shfl_xor(a0, 32, 64); a1 += __shfl_xor(a1, 32, 64);
        a2 += __shfl_xor(a2, 32, 64); a3 += __shfl_xor(a3, 32, 64);
        a4 += __shfl_xor(a4, 32, 64); a5 += __shfl_xor(a5, 32, 64);
        a6 += __shfl_xor(a6, 32, 64); a7 += __shfl_xor(a7, 32, 64);
        if (cih == 0 && col < 28) {
            float s[8] = {a0, a1, a2, a3, a4, a5, a6, a7};
            #pragma unroll
            for (int j = 0; j < 8; ++j) {
                const int cc = oct * 8 + j;
                float inv = g2[cc] * rsqrtf(v2[cc] + 1e-5f);
                float bb  = b2[cc] - m2[cc] * inv;
                h3t[cc * 32 + col] = fmaxf(-s[j] * inv + bb, 0.f);
            }
        }
    }
    __syncthreads();

    // ---- phase B: 1x1 adder 64->256 + BN3 + residual + ReLU ----
    {
        const int bl = tid & 63;          // co-quad: co = bl*4..+3
        const int pg = tid >> 6;          // px-quad group (wave id); px = pg*4..+3
        float4 c0 = {0,0,0,0}, c1 = c0, c2 = c0, c3 = c0;
        const float* hb = h3t + pg * 4;
        const float* wb = w3s + bl * 4;
        #pragma unroll 8
        for (int ci = 0; ci < 64; ++ci) {
            float4 h = *(const float4*)(hb + ci * 32);       // broadcast (wave-uniform)
            float4 w = *(const float4*)(wb + ci * 264);
            c0.x += fabsf(h.x - w.x); c0.y += fabsf(h.y - w.x); c0.z += fabsf(h.z - w.x); c0.w += fabsf(h.w - w.x);
            c1.x += fabsf(h.x - w.y); c1.y += fabsf(h.y - w.y); c1.z += fabsf(h.z - w.y); c1.w += fabsf(h.w - w.y);
            c2.x += fabsf(h.x - w.z); c2.y += fabsf(h.y - w.z); c2.z += fabsf(h.z - w.z); c2.w += fabsf(h.w - w.z);
            c3.x += fabsf(h.x - w.w); c3.y += fabsf(h.y - w.w); c3.z += fabsf(h.z - w.w); c3.w += fabsf(h.w - w.w);
        }
        if (pg < 7) {
            float4 accs[4] = {c0, c1, c2, c3};
            #pragma unroll
            for (int j = 0; j < 4; ++j) {
                const int co = bl * 4 + j;
                float inv = g3[co] * rsqrtf(v3[co] + 1e-5f);
                float bb  = b3[co] - m3[co] * inv;
                size_t obase = ((size_t)n * 256 + co) * 784 + Y * 28 + pg * 4;
                float4 r = *(const float4*)(x + obase);
                float4 o;
                o.x = fmaxf(-accs[j].x * inv + bb + r.x, 0.f);
                o.y = fmaxf(-accs[j].y * inv + bb + r.y, 0.f);
                o.z = fmaxf(-accs[j].z * inv + bb + r.z, 0.f);
                o.w = fmaxf(-accs[j].w * inv + bb + r.w, 0.f);
                *(float4*)(out + obase) = o;
            }
        }
    }
}

extern "C" void kernel_launch(void* const* d_in, const int* in_sizes, int n_in,
                              void* d_out, int out_size, void* d_ws, size_t ws_size,
                              hipStream_t stream) {
    const float* x  = (const float*)d_in[0];
    const float* w1 = (const float*)d_in[1];
    const float* wp = (const float*)d_in[2];
    const float* w2 = (const float*)d_in[3];
    const float* w3 = (const float*)d_in[4];
    const float* g1 = (const float*)d_in[5];
    const float* b1 = (const float*)d_in[6];
    const float* m1 = (const float*)d_in[7];
    const float* v1 = (const float*)d_in[8];
    const float* g2 = (const float*)d_in[9];
    const float* b2 = (const float*)d_in[10];
    const float* m2 = (const float*)d_in[11];
    const float* v2 = (const float*)d_in[12];
    const float* g3 = (const float*)d_in[13];
    const float* b3 = (const float*)d_in[14];
    const float* m3 = (const float*)d_in[15];
    const float* v3 = (const float*)d_in[16];
    float* out = (float*)d_out;

    float* wsf = (float*)d_ws;
    float* h2p = wsf;                 // 491520 floats
    float* w2t = wsf + 491520;        // 36864 floats [576 r][64 co]
    float* w3t = wsf + 528384;        // 16384 floats [64 ci][256 co]

    ka_fused<<<dim3(16, 2, 8), 448, 0, stream>>>(x, w1, wp, w2, w3,
                                                 g1, b1, m1, v1, h2p, w2t, w3t);
    kb_fused<<<dim3(28, 8), 512, 0, stream>>>(h2p, w2t, w3t, x,
                                              g2, b2, m2, v2, g3, b3, m3, v3, out);
}

// Round 19
// 63.464 us; speedup vs baseline: 1.1749x; 1.1749x over previous
//
#include <hip/hip_runtime.h>
#include <math.h>

#define PR 30            // padded rows of h2p
#define PC 32            // padded col stride of h2p

// 4px x 3kw taps for one co: window = {a.x,a.y,a.z,a.w,b.x,b.y}
__device__ __forceinline__ void tap3(const float4 a, const float2 b,
                                     const float w0, const float w1, const float w2,
                                     float4& acc) {
    acc.x += fabsf(a.x - w0) + fabsf(a.y - w1) + fabsf(a.z - w2);
    acc.y += fabsf(a.y - w0) + fabsf(a.z - w1) + fabsf(a.w - w2);
    acc.z += fabsf(a.z - w0) + fabsf(a.w - w1) + fabsf(b.x - w2);
    acc.w += fabsf(a.w - w0) + fabsf(b.x - w1) + fabsf(b.y - w2);
}

// =========== KA: 1x1 adder(256->64) + PEG depthwise 3x3 + BN1 + ReLU -> h2p ===========
// grid (16 cog, 2 yh, 8 n) = 256 blocks, block 448. Also emits w2t/w3t transposes.
__global__ __launch_bounds__(448) void ka_fused(const float* __restrict__ x,
                                                const float* __restrict__ w1,
                                                const float* __restrict__ wpeg,
                                                const float* __restrict__ w2,
                                                const float* __restrict__ w3,
                                                const float* __restrict__ g1,
                                                const float* __restrict__ b1,
                                                const float* __restrict__ m1,
                                                const float* __restrict__ v1,
                                                float* __restrict__ h2p,
                                                float* __restrict__ w2t,
                                                float* __restrict__ w3t) {
    __shared__ __align__(16) float smem[3072];   // wsA 1024 + h1t 2048 = 12 KB
    float* wsA = smem;            // [256 ci][4 co]
    float* h1t = smem + 1024;     // [4 co][16 rows][32]
    const int tid    = threadIdx.x;
    const int cobase = blockIdx.x * 4;
    const int yh     = blockIdx.y;
    const int n      = blockIdx.z;
    const int co     = tid / 112;
    const int rem    = tid % 112;
    const int row    = rem / 7;
    const int q      = rem % 7;

    // weight transposes for k3/k6 (consumed next launches; stream-ordered)
    {
        const int bid3 = blockIdx.x + 16 * (blockIdx.y + 2 * blockIdx.z);
        const int tg = bid3 * 448 + tid;
        if (tg < 36864) {
            int r = tg >> 6, c2 = tg & 63;
            w2t[tg] = w2[(size_t)c2 * 576 + r];             // w2t[r*64+co]
        } else if (tg < 53248) {
            int i = tg - 36864;
            int ci = i >> 8, c2 = i & 255;
            w3t[i] = w3[(size_t)c2 * 64 + ci];              // w3t[ci*256+co]
        }
    }

    for (int idx = tid; idx < 1024; idx += 448) {
        int c2 = idx >> 8, ci = idx & 255;
        wsA[ci * 4 + c2] = w1[(size_t)(cobase + c2) * 256 + ci];
    }
    for (int idx = tid; idx < 512; idx += 448)
        ((float4*)h1t)[idx] = make_float4(0.f, 0.f, 0.f, 0.f);
    __syncthreads();

    const int gy = yh * 14 - 1 + row;
    if (gy >= 0 && gy < 28) {
        float4 acc = {0.f, 0.f, 0.f, 0.f};
        const float* xp = x + (size_t)n * 256 * 784 + gy * 28 + q * 4;
        #pragma unroll 8
        for (int ci = 0; ci < 256; ++ci) {
            float4 u = *(const float4*)(xp + (size_t)ci * 784);
            float w  = wsA[ci * 4 + co];
            acc.x += fabsf(u.x - w); acc.y += fabsf(u.y - w);
            acc.z += fabsf(u.z - w); acc.w += fabsf(u.w - w);
        }
        float* hd = h1t + co * 512 + row * 32 + 1 + q * 4;
        hd[0] = -acc.x; hd[1] = -acc.y; hd[2] = -acc.z; hd[3] = -acc.w;
    }
    __syncthreads();

    if (row < 14) {
        const int c  = cobase + co;
        const int oy = yh * 14 + row;
        const float* wc = wpeg + c * 9;
        const float* hb = h1t + co * 512 + row * 32 + q * 4;
        float4 acc = {0.f, 0.f, 0.f, 0.f};
        #pragma unroll
        for (int kh = 0; kh < 3; ++kh) {
            float4 a  = *(const float4*)(hb + kh * 32);
            float2 bv = *(const float2*)(hb + kh * 32 + 4);
            tap3(a, bv, wc[kh * 3 + 0], wc[kh * 3 + 1], wc[kh * 3 + 2], acc);
        }
        float inv = g1[c] * rsqrtf(v1[c] + 1e-5f);
        float bb  = b1[c] - m1[c] * inv;
        float* op = h2p + ((size_t)(n * 64 + c) * PR + oy + 1) * PC + 1 + q * 4;
        op[0] = fmaxf(-acc.x * inv + bb, 0.f);
        op[1] = fmaxf(-acc.y * inv + bb, 0.f);
        op[2] = fmaxf(-acc.z * inv + bb, 0.f);
        op[3] = fmaxf(-acc.w * inv + bb, 0.f);
    }
    for (int idx = tid; idx < 352; idx += 448) {
        if (idx < 224) {
            int rr = idx >> 4, k = idx & 15;
            int cc = k >> 2, kk = k & 3;
            int col = kk ? 28 + kk : 0;
            h2p[((size_t)(n * 64 + cobase + cc) * PR + yh * 14 + 1 + rr) * PC + col] = 0.f;
        } else {
            int j = idx - 224;
            int cc = j >> 5, col = j & 31;
            int prow = yh ? 29 : 0;
            h2p[((size_t)(n * 64 + cobase + cc) * PR + prow) * PC + col] = 0.f;
        }
    }
}

// =========== K3: 3x3 adder partials (16-ci quarter) -> h3part ===========
// grid (7 Yq, 4 ciQ, 8 n) = 224 blocks, block 512 = 8 waves.
// Wave = co-oct (weights = LDS f4 BROADCAST, conflict-free).
// Lane = col(32) x cih(2). Thread: 4 rows x 1 col x 8 co x 8 ci.
// Ratio: 1152 VALU cyc vs ~320 LDS cyc per ci -> VALU-dense.
__global__ __launch_bounds__(512) void k3_part(const float* __restrict__ h2p,
                                               const float* __restrict__ w2t,
                                               float* __restrict__ h3part) {
    __shared__ __align__(16) float h2t[3456];    // [16 ci][6 rows][36]
    __shared__ __align__(16) float wt[9792];     // [16 ci][9 tap][68]
    const int tid  = threadIdx.x;
    const int lane = tid & 63;
    const int oct  = __builtin_amdgcn_readfirstlane(tid >> 6);   // 0..7
    const int col  = lane & 31;
    const int cih  = lane >> 5;          // 0..1
    const int Y0   = blockIdx.x * 4;     // output rows Y0..Y0+3
    const int ciQ  = blockIdx.y;         // ci quarter
    const int n    = blockIdx.z;

    // stage h2t: 16 ci, padded rows Y0..Y0+5, cols 0..31 (f4 coalesced)
    for (int i = tid; i < 768; i += 512) {
        int ci = i / 48, rem = i % 48;
        int r = rem >> 3, c4 = rem & 7;
        *(float4*)(h2t + ci * 216 + r * 36 + c4 * 4) =
            *(const float4*)(h2p + ((size_t)(n * 64 + ciQ * 16 + ci) * PR + Y0 + r) * PC + c4 * 4);
    }
    // stage wt: rows = ci*9+tap (global r = ciQ*144 + row), 64 co (f4 coalesced)
    for (int i = tid; i < 2304; i += 512) {
        int row = i >> 4, c4 = i & 15;
        *(float4*)(wt + row * 68 + c4 * 4) =
            *(const float4*)(w2t + ((size_t)ciQ * 144 + row) * 64 + c4 * 4);
    }
    __syncthreads();

    float acc[4][8];
    #pragma unroll
    for (int r = 0; r < 4; ++r)
        #pragma unroll
        for (int j = 0; j < 8; ++j) acc[r][j] = 0.f;

    #pragma unroll 2
    for (int i = 0; i < 8; ++i) {
        const int ci = cih * 8 + i;
        float win[6][3];
        #pragma unroll
        for (int r = 0; r < 6; ++r)
            #pragma unroll
            for (int kw = 0; kw < 3; ++kw)
                win[r][kw] = h2t[ci * 216 + r * 36 + col + kw];
        const float* wrow = wt + ci * 612 + oct * 8;
        #pragma unroll
        for (int kh = 0; kh < 3; ++kh) {
            #pragma unroll
            for (int kw = 0; kw < 3; ++kw) {
                float4 wa = *(const float4*)(wrow + (kh * 3 + kw) * 68);
                float4 wb = *(const float4*)(wrow + (kh * 3 + kw) * 68 + 4);
                #pragma unroll
                for (int r = 0; r < 4; ++r) {
                    const float xv = win[r + kh][kw];
                    acc[r][0] += fabsf(xv - wa.x); acc[r][1] += fabsf(xv - wa.y);
                    acc[r][2] += fabsf(xv - wa.z); acc[r][3] += fabsf(xv - wa.w);
                    acc[r][4] += fabsf(xv - wb.x); acc[r][5] += fabsf(xv - wb.y);
                    acc[r][6] += fabsf(xv - wb.z); acc[r][7] += fabsf(xv - wb.w);
                }
            }
        }
    }
    // 2-way ci reduce across lane bit 5
    #pragma unroll
    for (int r = 0; r < 4; ++r)
        #pragma unroll
        for (int j = 0; j < 8; ++j)
            acc[r][j] += __shfl_xor(acc[r][j], 32, 64);

    if (cih == 0 && col < 28) {
        #pragma unroll
        for (int r = 0; r < 4; ++r)
            #pragma unroll
            for (int j = 0; j < 8; ++j)
                h3part[(((size_t)ciQ * 8 + n) * 64 + oct * 8 + j) * 784 + (Y0 + r) * 28 + col] = acc[r][j];
    }
}

// =========== K6: sum 4 h3 partials + BN2 + ReLU (staging) + 1x1 adder 64->256 + BN3 + res + ReLU ===========
// grid (28 Y, 8 n) = 224 blocks, block 512.
__global__ __launch_bounds__(512) void k6_fused(const float* __restrict__ h3part,
                                                const float* __restrict__ w3t,
                                                const float* __restrict__ x,
                                                const float* __restrict__ g2,
                                                const float* __restrict__ b2,
                                                const float* __restrict__ m2,
                                                const float* __restrict__ v2,
                                                const float* __restrict__ g3,
                                                const float* __restrict__ b3,
                                                const float* __restrict__ m3,
                                                const float* __restrict__ v3,
                                                float* __restrict__ out) {
    __shared__ __align__(16) float h3t[2048];    // [64 ch][32]
    __shared__ __align__(16) float w3s[16896];   // [64 ci][264]
    const int tid = threadIdx.x;
    const int Y   = blockIdx.x;
    const int n   = blockIdx.y;

    // stage h3t: sum 4 ci-quarter partials + BN2 + ReLU  (448 active threads)
    if (tid < 448) {
        const int co = tid / 7, c4 = tid % 7;
        size_t base = ((size_t)n * 64 + co) * 784 + Y * 28 + c4 * 4;
        const size_t qstride = (size_t)8 * 64 * 784;
        float4 s = *(const float4*)(h3part + base);
        #pragma unroll
        for (int qq = 1; qq < 4; ++qq) {
            float4 t = *(const float4*)(h3part + qq * qstride + base);
            s.x += t.x; s.y += t.y; s.z += t.z; s.w += t.w;
        }
        float inv = g2[co] * rsqrtf(v2[co] + 1e-5f);
        float bb  = b2[co] - m2[co] * inv;
        float4 o;
        o.x = fmaxf(-s.x * inv + bb, 0.f);
        o.y = fmaxf(-s.y * inv + bb, 0.f);
        o.z = fmaxf(-s.z * inv + bb, 0.f);
        o.w = fmaxf(-s.w * inv + bb, 0.f);
        *(float4*)(h3t + co * 32 + c4 * 4) = o;
    }
    // stage w3s from pre-transposed w3t (f4, coalesced)
    for (int iq = tid; iq < 4096; iq += 512) {
        int ci = iq >> 6, cq = iq & 63;
        *(float4*)(w3s + ci * 264 + cq * 4) =
            *(const float4*)(w3t + (size_t)ci * 256 + cq * 4);
    }
    __syncthreads();

    // 1x1 adder 64->256 + BN3 + residual + ReLU
    {
        const int bl = tid & 63;          // co-quad: co = bl*4..+3
        const int pg = tid >> 6;          // px-quad group; px = pg*4..+3
        float4 c0 = {0,0,0,0}, c1 = c0, c2 = c0, c3 = c0;
        const float* hb = h3t + pg * 4;
        const float* wb = w3s + bl * 4;
        #pragma unroll 8
        for (int ci = 0; ci < 64; ++ci) {
            float4 h = *(const float4*)(hb + ci * 32);       // broadcast
            float4 w = *(const float4*)(wb + ci * 264);
            c0.x += fabsf(h.x - w.x); c0.y += fabsf(h.y - w.x); c0.z += fabsf(h.z - w.x); c0.w += fabsf(h.w - w.x);
            c1.x += fabsf(h.x - w.y); c1.y += fabsf(h.y - w.y); c1.z += fabsf(h.z - w.y); c1.w += fabsf(h.w - w.y);
            c2.x += fabsf(h.x - w.z); c2.y += fabsf(h.y - w.z); c2.z += fabsf(h.z - w.z); c2.w += fabsf(h.w - w.z);
            c3.x += fabsf(h.x - w.w); c3.y += fabsf(h.y - w.w); c3.z += fabsf(h.z - w.w); c3.w += fabsf(h.w - w.w);
        }
        if (pg < 7) {
            float4 accs[4] = {c0, c1, c2, c3};
            #pragma unroll
            for (int j = 0; j < 4; ++j) {
                const int co = bl * 4 + j;
                float inv = g3[co] * rsqrtf(v3[co] + 1e-5f);
                float bb  = b3[co] - m3[co] * inv;
                size_t obase = ((size_t)n * 256 + co) * 784 + Y * 28 + pg * 4;
                float4 r = *(const float4*)(x + obase);
                float4 o;
                o.x = fmaxf(-accs[j].x * inv + bb + r.x, 0.f);
                o.y = fmaxf(-accs[j].y * inv + bb + r.y, 0.f);
                o.z = fmaxf(-accs[j].z * inv + bb + r.z, 0.f);
                o.w = fmaxf(-accs[j].w * inv + bb + r.w, 0.f);
                *(float4*)(out + obase) = o;
            }
        }
    }
}

extern "C" void kernel_launch(void* const* d_in, const int* in_sizes, int n_in,
                              void* d_out, int out_size, void* d_ws, size_t ws_size,
                              hipStream_t stream) {
    const float* x  = (const float*)d_in[0];
    const float* w1 = (const float*)d_in[1];
    const float* wp = (const float*)d_in[2];
    const float* w2 = (const float*)d_in[3];
    const float* w3 = (const float*)d_in[4];
    const float* g1 = (const float*)d_in[5];
    const float* b1 = (const float*)d_in[6];
    const float* m1 = (const float*)d_in[7];
    const float* v1 = (const float*)d_in[8];
    const float* g2 = (const float*)d_in[9];
    const float* b2 = (const float*)d_in[10];
    const float* m2 = (const float*)d_in[11];
    const float* v2 = (const float*)d_in[12];
    const float* g3 = (const float*)d_in[13];
    const float* b3 = (const float*)d_in[14];
    const float* m3 = (const float*)d_in[15];
    const float* v3 = (const float*)d_in[16];
    float* out = (float*)d_out;

    float* wsf     = (float*)d_ws;
    float* h2p     = wsf;                 // 491520 floats
    float* w2t     = wsf + 491520;        // 36864 floats [576 r][64 co]
    float* w3t     = wsf + 528384;        // 16384 floats [64 ci][256 co]
    float* h3part  = wsf + 544768;        // 4*8*64*784 = 1605632 floats

    ka_fused<<<dim3(16, 2, 8), 448, 0, stream>>>(x, w1, wp, w2, w3,
                                                 g1, b1, m1, v1, h2p, w2t, w3t);
    k3_part<<<dim3(7, 4, 8), 512, 0, stream>>>(h2p, w2t, h3part);
    k6_fused<<<dim3(28, 8), 512, 0, stream>>>(h3part, w3t, x,
                                              g2, b2, m2, v2, g3, b3, m3, v3, out);
}